// Round 9
// baseline (272.549 us; speedup 1.0000x reference)
//
#include <hip/hip_runtime.h>
#include <hip/hip_bf16.h>
#include <math.h>

#define NUM_OBJECTS 80000
#define EPS_W 1e-5f
#define EPS_A 1e-7f

// packed per-object accumulator (u32): bits [31:8] = sum(loss) in 2^18 fixed
// point, bits [7:0] = count.
#define LOSS_SCALE_F 262144.0f   // 2^18
#define INV_LOSS_SCALE_F (1.0f / 262144.0f)

#define TABLE_VEC4 20000
#define ZERO_VEC16 20001
#define NPASS 10
#define ROT 39119   // index rotation per probe pass (9*ROT < N)

typedef float f32x4u __attribute__((ext_vector_type(4), aligned(4)));

__global__ void zero_ws(uint4* __restrict__ ws) {
    int i = blockIdx.x * blockDim.x + threadIdx.x;
    if (i < ZERO_VEC16) ws[i] = make_uint4(0u, 0u, 0u, 0u);
}

__device__ __forceinline__ void corner_minmax(float X, float Y, float Wc,
                                              float& minx, float& maxx,
                                              float& miny, float& maxy) {
    float wd = fmaxf(Wc, EPS_W);
    float r  = __builtin_amdgcn_rcpf(wd);
    float xi = X * r;
    float yi = Y * r;
    minx = fminf(minx, xi); maxx = fmaxf(maxx, xi);
    miny = fminf(miny, yi); maxy = fmaxf(maxy, yi);
}

__device__ __forceinline__ void compute_box(
        int i,
        const float* __restrict__ pred, const float* __restrict__ gt2d,
        const float* __restrict__ l2i, const float* __restrict__ imgsh,
        const int* __restrict__ ids,
        unsigned int& pk, int& oid) {
    f32x4u pa = *(const f32x4u*)(pred + 7 * (size_t)i);      // x y z l
    f32x4u pb = *(const f32x4u*)(pred + 7 * (size_t)i + 3);  // l w h yaw
    const float4* M = (const float4*)(l2i + 16 * (size_t)i);
    float4 M0 = M[0];
    float4 M1 = M[1];
    float4 M2 = M[2];
    float4 g   = ((const float4*)gt2d)[i];
    float2 hwd = ((const float2*)imgsh)[i];
    oid = ids[i];

    float x = pa.x, y = pa.y, z = pa.z;
    float hl = 0.5f * pa.w, hw = 0.5f * pb.y, hh = 0.5f * pb.z;
    float yaw = pb.w;
    float s, c;
    __sincosf(yaw, &s, &c);

    float bx = M0.x * x + M0.y * y + M0.z * z + M0.w;
    float by = M1.x * x + M1.y * y + M1.z * z + M1.w;
    float bw = M2.x * x + M2.y * y + M2.z * z + M2.w;
    float Ax = (M0.x * c + M0.y * s) * hl;
    float Ay = (M1.x * c + M1.y * s) * hl;
    float Aw = (M2.x * c + M2.y * s) * hl;
    float Bx = (M0.y * c - M0.x * s) * hw;
    float By = (M1.y * c - M1.x * s) * hw;
    float Bw = (M2.y * c - M2.x * s) * hw;
    float Cx = M0.z * hh;
    float Cy = M1.z * hh;
    float Cw = M2.z * hh;

    float xp = bx + Ax, xm = bx - Ax;
    float X0 = xp + Bx, X1 = xp - Bx, X2 = xm + Bx, X3 = xm - Bx;
    float yp = by + Ay, ym = by - Ay;
    float Y0 = yp + By, Y1 = yp - By, Y2 = ym + By, Y3 = ym - By;
    float wp = bw + Aw, wm = bw - Aw;
    float W0 = wp + Bw, W1 = wp - Bw, W2 = wm + Bw, W3 = wm - Bw;

    float minx = 1e30f, maxx = -1e30f, miny = 1e30f, maxy = -1e30f;
    corner_minmax(X0 + Cx, Y0 + Cy, W0 + Cw, minx, maxx, miny, maxy);
    corner_minmax(X0 - Cx, Y0 - Cy, W0 - Cw, minx, maxx, miny, maxy);
    corner_minmax(X1 + Cx, Y1 + Cy, W1 + Cw, minx, maxx, miny, maxy);
    corner_minmax(X1 - Cx, Y1 - Cy, W1 - Cw, minx, maxx, miny, maxy);
    corner_minmax(X2 + Cx, Y2 + Cy, W2 + Cw, minx, maxx, miny, maxy);
    corner_minmax(X2 - Cx, Y2 - Cy, W2 - Cw, minx, maxx, miny, maxy);
    corner_minmax(X3 + Cx, Y3 + Cy, W3 + Cw, minx, maxx, miny, maxy);
    corner_minmax(X3 - Cx, Y3 - Cy, W3 - Cw, minx, maxx, miny, maxy);

    float H = hwd.x, W = hwd.y;
    float px1 = fminf(fmaxf(minx, 0.f), W);
    float px2 = fminf(fmaxf(maxx, 0.f), W);
    float py1 = fminf(fmaxf(miny, 0.f), H);
    float py2 = fminf(fmaxf(maxy, 0.f), H);

    float ix1 = fmaxf(px1, g.x);
    float iy1 = fmaxf(py1, g.y);
    float ix2 = fminf(px2, g.z);
    float iy2 = fminf(py2, g.w);
    float inter = fmaxf(ix2 - ix1, 0.f) * fmaxf(iy2 - iy1, 0.f);
    float pa2 = (px2 - px1) * (py2 - py1);
    float ga = (g.z - g.x) * (g.w - g.y);
    float uni = pa2 + ga - inter + EPS_A;
    float iou = inter / uni;

    float cx1 = fminf(px1, g.x);
    float cy1 = fminf(py1, g.y);
    float cx2 = fmaxf(px2, g.z);
    float cy2 = fmaxf(py2, g.w);
    float carea = fmaxf(cx2 - cx1, 0.f) * fmaxf(cy2 - cy1, 0.f) + EPS_A;
    float giou = iou - (carea - uni) / carea;
    float loss = 1.0f - giou;   // >= 0

    pk = ((unsigned int)(loss * LOSS_SCALE_F + 0.5f) << 8) | 1u;
}

__global__ void __launch_bounds__(256) loss_kernel(
        const float* __restrict__ pred, const float* __restrict__ gt2d,
        const float* __restrict__ l2i, const float* __restrict__ imgsh,
        const int* __restrict__ ids,
        unsigned int* __restrict__ table, int n) {
    int i = blockIdx.x * blockDim.x + threadIdx.x;
    if (i >= n) return;
    unsigned int pk; int oid;
    compute_box(i, pred, gt2d, l2i, imgsh, ids, pk, oid);
    atomicAdd(&table[oid], pk);
}

// ---- diagnostic probes (run after seg_reduce; do not affect d_out) ----
__global__ void __launch_bounds__(256) probe_gather(
        const float* __restrict__ pred, const float* __restrict__ gt2d,
        const float* __restrict__ l2i, const float* __restrict__ imgsh,
        const int* __restrict__ ids, int n) {
    int i = blockIdx.x * blockDim.x + threadIdx.x;
    if (i >= n) return;
#pragma unroll 1
    for (int k = 0; k < NPASS; ++k) {
        int idx = i + k * ROT;
        if (idx >= n) idx -= n;
        unsigned int pk; int oid;
        compute_box(idx, pred, gt2d, l2i, imgsh, ids, pk, oid);
        asm volatile("" :: "v"(pk), "v"(oid));   // keep alive, no DCE
    }
}

__global__ void __launch_bounds__(256) probe_atomic(
        const float* __restrict__ pred, const float* __restrict__ gt2d,
        const float* __restrict__ l2i, const float* __restrict__ imgsh,
        const int* __restrict__ ids,
        unsigned int* __restrict__ dummy, int n) {
    int i = blockIdx.x * blockDim.x + threadIdx.x;
    if (i >= n) return;
#pragma unroll 1
    for (int k = 0; k < NPASS; ++k) {
        int idx = i + k * ROT;
        if (idx >= n) idx -= n;
        unsigned int pk; int oid;
        compute_box(idx, pred, gt2d, l2i, imgsh, ids, pk, oid);
        atomicAdd(&dummy[oid], pk);   // never read; state irrelevant
    }
}

__global__ void __launch_bounds__(256) seg_reduce(
        const uint4* __restrict__ table4,
        float* __restrict__ acc,
        unsigned int* __restrict__ ticket,
        float* __restrict__ out) {
    int i = blockIdx.x * blockDim.x + threadIdx.x;
    float sm = 0.f, pr = 0.f;
    if (i < TABLE_VEC4) {
        uint4 w = table4[i];
        unsigned int c0 = w.x & 0xFFu, c1 = w.y & 0xFFu;
        unsigned int c2 = w.z & 0xFFu, c3 = w.w & 0xFFu;
        if (c0) { sm += (float)(w.x >> 8) * INV_LOSS_SCALE_F / (float)c0; pr += 1.f; }
        if (c1) { sm += (float)(w.y >> 8) * INV_LOSS_SCALE_F / (float)c1; pr += 1.f; }
        if (c2) { sm += (float)(w.z >> 8) * INV_LOSS_SCALE_F / (float)c2; pr += 1.f; }
        if (c3) { sm += (float)(w.w >> 8) * INV_LOSS_SCALE_F / (float)c3; pr += 1.f; }
    }
#pragma unroll
    for (int off = 32; off > 0; off >>= 1) {
        sm += __shfl_down(sm, off);
        pr += __shfl_down(pr, off);
    }
    __shared__ float ssm[4], spr[4];
    int lane = threadIdx.x & 63;
    int wid = threadIdx.x >> 6;
    if (lane == 0) { ssm[wid] = sm; spr[wid] = pr; }
    __syncthreads();
    if (threadIdx.x == 0) {
        float a = 0.f, b2 = 0.f;
#pragma unroll
        for (int k = 0; k < 4; ++k) { a += ssm[k]; b2 += spr[k]; }
        atomicAdd(&acc[0], a);
        atomicAdd(&acc[1], b2);
        __threadfence();
        unsigned int old = atomicAdd(ticket, 1u);
        if (old == gridDim.x - 1) {
            float s = atomicAdd(&acc[0], 0.f);
            float pcnt = atomicAdd(&acc[1], 0.f);
            out[0] = s / pcnt;   // LOSS_WEIGHT == 1.0
        }
    }
}

extern "C" void kernel_launch(void* const* d_in, const int* in_sizes, int n_in,
                              void* d_out, int out_size, void* d_ws, size_t ws_size,
                              hipStream_t stream) {
    const float* pred  = (const float*)d_in[0];
    const float* gt2d  = (const float*)d_in[1];
    const float* l2i   = (const float*)d_in[2];
    const float* imgsh = (const float*)d_in[3];
    const int*   ids   = (const int*)d_in[4];
    float* out = (float*)d_out;

    int n = in_sizes[0] / 7;
    int block = 256;

    unsigned int* table  = (unsigned int*)d_ws;
    float*        acc    = (float*)(table + NUM_OBJECTS);  // 2 floats
    unsigned int* ticket = (unsigned int*)(acc + 2);       // 1 u32
    unsigned int* dummy  = (unsigned int*)((char*)d_ws + (1 << 19));  // 512KB off

    int gridz = (ZERO_VEC16 + block - 1) / block;
    zero_ws<<<gridz, block, 0, stream>>>((uint4*)d_ws);

    int grid1 = (n + block - 1) / block;
    loss_kernel<<<grid1, block, 0, stream>>>(pred, gt2d, l2i, imgsh, ids, table, n);

    int grid2 = (TABLE_VEC4 + block - 1) / block;
    seg_reduce<<<grid2, block, 0, stream>>>((const uint4*)table, acc, ticket, out);

    // ---- measurement probes (output-neutral) ----
    probe_gather<<<grid1, block, 0, stream>>>(pred, gt2d, l2i, imgsh, ids, n);
    probe_atomic<<<grid1, block, 0, stream>>>(pred, gt2d, l2i, imgsh, ids, dummy, n);
}

// Round 10
// 36.033 us; speedup vs baseline: 7.5639x; 7.5639x over previous
//
#include <hip/hip_runtime.h>
#include <hip/hip_bf16.h>
#include <math.h>

#define NUM_OBJECTS 80000
#define NXCD 8
#define EPS_W 1e-5f
#define EPS_A 1e-7f

// packed per-object accumulator (u32): bits [31:8] = sum(loss) in 2^18 fixed
// point, bits [7:0] = count. Per-slice and summed-over-8-slices both fit.
#define LOSS_SCALE_F 262144.0f   // 2^18
#define INV_LOSS_SCALE_F (1.0f / 262144.0f)

// s_getreg_b32 hwreg(HW_REG_XCC_ID=20, offset=0, size=4)  [measured: m09]
#define XCC_ID_GETREG (((4 - 1) << 11) | (0 << 6) | 20)

#define TABLE_VEC4 (NUM_OBJECTS / 4)               // 20000 (one slice)
#define ZERO8_VEC16 (NXCD * NUM_OBJECTS / 4 + 1)   // 160001 (8 slices + acc/ticket)
#define ZERO1_VEC16 (NUM_OBJECTS / 4 + 1)          // 20001

typedef float f32x4u __attribute__((ext_vector_type(4), aligned(4)));

__global__ void zero_ws(uint4* __restrict__ ws, int nvec) {
    int i = blockIdx.x * blockDim.x + threadIdx.x;
    if (i < nvec) ws[i] = make_uint4(0u, 0u, 0u, 0u);
}

__device__ __forceinline__ void corner_minmax(float X, float Y, float Wc,
                                              float& minx, float& maxx,
                                              float& miny, float& maxy) {
    float wd = fmaxf(Wc, EPS_W);
    float r  = __builtin_amdgcn_rcpf(wd);   // v_rcp_f32, ~1 ulp
    float xi = X * r;
    float yi = Y * r;
    minx = fminf(minx, xi); maxx = fmaxf(maxx, xi);
    miny = fminf(miny, yi); maxy = fmaxf(maxy, yi);
}

__device__ __forceinline__ void compute_box(
        int i,
        const float* __restrict__ pred, const float* __restrict__ gt2d,
        const float* __restrict__ l2i, const float* __restrict__ imgsh,
        const int* __restrict__ ids,
        unsigned int& pk, int& oid) {
    f32x4u pa = *(const f32x4u*)(pred + 7 * (size_t)i);      // x y z l
    f32x4u pb = *(const f32x4u*)(pred + 7 * (size_t)i + 3);  // l w h yaw
    const float4* M = (const float4*)(l2i + 16 * (size_t)i);
    float4 M0 = M[0];
    float4 M1 = M[1];
    float4 M2 = M[2];
    float4 g   = ((const float4*)gt2d)[i];
    float2 hwd = ((const float2*)imgsh)[i];
    oid = ids[i];

    float x = pa.x, y = pa.y, z = pa.z;
    float hl = 0.5f * pa.w, hw = 0.5f * pb.y, hh = 0.5f * pb.z;
    float yaw = pb.w;
    float s, c;
    __sincosf(yaw, &s, &c);

    // row·corner = b + sx*A + sy*B + sz*C  (affine in the sign triple)
    float bx = M0.x * x + M0.y * y + M0.z * z + M0.w;
    float by = M1.x * x + M1.y * y + M1.z * z + M1.w;
    float bw = M2.x * x + M2.y * y + M2.z * z + M2.w;
    float Ax = (M0.x * c + M0.y * s) * hl;
    float Ay = (M1.x * c + M1.y * s) * hl;
    float Aw = (M2.x * c + M2.y * s) * hl;
    float Bx = (M0.y * c - M0.x * s) * hw;
    float By = (M1.y * c - M1.x * s) * hw;
    float Bw = (M2.y * c - M2.x * s) * hw;
    float Cx = M0.z * hh;
    float Cy = M1.z * hh;
    float Cw = M2.z * hh;

    float xp = bx + Ax, xm = bx - Ax;
    float X0 = xp + Bx, X1 = xp - Bx, X2 = xm + Bx, X3 = xm - Bx;
    float yp = by + Ay, ym = by - Ay;
    float Y0 = yp + By, Y1 = yp - By, Y2 = ym + By, Y3 = ym - By;
    float wp = bw + Aw, wm = bw - Aw;
    float W0 = wp + Bw, W1 = wp - Bw, W2 = wm + Bw, W3 = wm - Bw;

    float minx = 1e30f, maxx = -1e30f, miny = 1e30f, maxy = -1e30f;
    corner_minmax(X0 + Cx, Y0 + Cy, W0 + Cw, minx, maxx, miny, maxy);
    corner_minmax(X0 - Cx, Y0 - Cy, W0 - Cw, minx, maxx, miny, maxy);
    corner_minmax(X1 + Cx, Y1 + Cy, W1 + Cw, minx, maxx, miny, maxy);
    corner_minmax(X1 - Cx, Y1 - Cy, W1 - Cw, minx, maxx, miny, maxy);
    corner_minmax(X2 + Cx, Y2 + Cy, W2 + Cw, minx, maxx, miny, maxy);
    corner_minmax(X2 - Cx, Y2 - Cy, W2 - Cw, minx, maxx, miny, maxy);
    corner_minmax(X3 + Cx, Y3 + Cy, W3 + Cw, minx, maxx, miny, maxy);
    corner_minmax(X3 - Cx, Y3 - Cy, W3 - Cw, minx, maxx, miny, maxy);

    float H = hwd.x, W = hwd.y;
    float px1 = fminf(fmaxf(minx, 0.f), W);
    float px2 = fminf(fmaxf(maxx, 0.f), W);
    float py1 = fminf(fmaxf(miny, 0.f), H);
    float py2 = fminf(fmaxf(maxy, 0.f), H);

    float ix1 = fmaxf(px1, g.x);
    float iy1 = fmaxf(py1, g.y);
    float ix2 = fminf(px2, g.z);
    float iy2 = fminf(py2, g.w);
    float inter = fmaxf(ix2 - ix1, 0.f) * fmaxf(iy2 - iy1, 0.f);
    float pa2 = (px2 - px1) * (py2 - py1);
    float ga = (g.z - g.x) * (g.w - g.y);
    float uni = pa2 + ga - inter + EPS_A;
    float iou = inter / uni;

    float cx1 = fminf(px1, g.x);
    float cy1 = fminf(py1, g.y);
    float cx2 = fmaxf(px2, g.z);
    float cy2 = fmaxf(py2, g.w);
    float carea = fmaxf(cx2 - cx1, 0.f) * fmaxf(cy2 - cy1, 0.f) + EPS_A;
    float giou = iou - (carea - uni) / carea;
    float loss = 1.0f - giou;   // >= 0

    pk = ((unsigned int)(loss * LOSS_SCALE_F + 0.5f) << 8) | 1u;
}

template <int NT>
__global__ void __launch_bounds__(256) loss_kernel(
        const float* __restrict__ pred, const float* __restrict__ gt2d,
        const float* __restrict__ l2i, const float* __restrict__ imgsh,
        const int* __restrict__ ids,
        unsigned int* __restrict__ table, int n) {
    int i = blockIdx.x * blockDim.x + threadIdx.x;
    if (i >= n) return;
    unsigned int pk; int oid;
    compute_box(i, pred, gt2d, l2i, imgsh, ids, pk, oid);

    if (NT == NXCD) {
        // per-XCD slice + L2-local atomic: global_atomic_add with NO sc bits
        // executes the RMW in this XCD's L2 (16 ch, write-back) instead of the
        // device coherence point (~35 G/s wall measured in R9). Slices are
        // XCD-private -> no cross-XCD aliasing; vmcnt(0) drains the op before
        // wave-end so the kernel-end L2 flush can't miss it.
        unsigned int xcc = __builtin_amdgcn_s_getreg(XCC_ID_GETREG) & 7u;
        unsigned int* p = table + (size_t)xcc * NUM_OBJECTS + oid;
        asm volatile("global_atomic_add %0, %1, off\n\t"
                     "s_waitcnt vmcnt(0)"
                     :: "v"(p), "v"(pk) : "memory");
    } else {
        atomicAdd(&table[oid], pk);
    }
}

template <int NT>
__global__ void __launch_bounds__(256) seg_reduce(
        const unsigned int* __restrict__ table,  // NT x NUM_OBJECTS
        float* __restrict__ acc,                 // acc[0]=sum of means, acc[1]=n present
        unsigned int* __restrict__ ticket,
        float* __restrict__ out) {
    int i = blockIdx.x * blockDim.x + threadIdx.x;
    float sm = 0.f, pr = 0.f;
    if (i < TABLE_VEC4) {
        unsigned int sf0 = 0, sf1 = 0, sf2 = 0, sf3 = 0;
        unsigned int c0 = 0, c1 = 0, c2 = 0, c3 = 0;
#pragma unroll
        for (int tt = 0; tt < NT; ++tt) {
            uint4 w = ((const uint4*)(table + (size_t)tt * NUM_OBJECTS))[i];
            sf0 += w.x >> 8; c0 += w.x & 0xFFu;
            sf1 += w.y >> 8; c1 += w.y & 0xFFu;
            sf2 += w.z >> 8; c2 += w.z & 0xFFu;
            sf3 += w.w >> 8; c3 += w.w & 0xFFu;
        }
        if (c0) { sm += (float)sf0 * INV_LOSS_SCALE_F / (float)c0; pr += 1.f; }
        if (c1) { sm += (float)sf1 * INV_LOSS_SCALE_F / (float)c1; pr += 1.f; }
        if (c2) { sm += (float)sf2 * INV_LOSS_SCALE_F / (float)c2; pr += 1.f; }
        if (c3) { sm += (float)sf3 * INV_LOSS_SCALE_F / (float)c3; pr += 1.f; }
    }
#pragma unroll
    for (int off = 32; off > 0; off >>= 1) {
        sm += __shfl_down(sm, off);
        pr += __shfl_down(pr, off);
    }
    __shared__ float ssm[4], spr[4];
    int lane = threadIdx.x & 63;
    int wid = threadIdx.x >> 6;
    if (lane == 0) { ssm[wid] = sm; spr[wid] = pr; }
    __syncthreads();
    if (threadIdx.x == 0) {
        float a = 0.f, b2 = 0.f;
#pragma unroll
        for (int k = 0; k < 4; ++k) { a += ssm[k]; b2 += spr[k]; }
        atomicAdd(&acc[0], a);
        atomicAdd(&acc[1], b2);
        __threadfence();
        unsigned int old = atomicAdd(ticket, 1u);
        if (old == gridDim.x - 1) {
            // atomic reads hit the coherence point (cross-XCD safe)
            float s = atomicAdd(&acc[0], 0.f);
            float pcnt = atomicAdd(&acc[1], 0.f);
            out[0] = s / pcnt;   // LOSS_WEIGHT == 1.0
        }
    }
}

extern "C" void kernel_launch(void* const* d_in, const int* in_sizes, int n_in,
                              void* d_out, int out_size, void* d_ws, size_t ws_size,
                              hipStream_t stream) {
    const float* pred  = (const float*)d_in[0];
    const float* gt2d  = (const float*)d_in[1];
    const float* l2i   = (const float*)d_in[2];
    const float* imgsh = (const float*)d_in[3];
    const int*   ids   = (const int*)d_in[4];
    float* out = (float*)d_out;

    int n = in_sizes[0] / 7;
    int block = 256;

    bool xcd8 = ws_size >= (size_t)NXCD * NUM_OBJECTS * sizeof(unsigned int) + 16;
    int nt = xcd8 ? NXCD : 1;

    unsigned int* table  = (unsigned int*)d_ws;
    float*        acc    = (float*)(table + (size_t)nt * NUM_OBJECTS);  // 2 floats
    unsigned int* ticket = (unsigned int*)(acc + 2);                    // 1 u32

    int nvec = xcd8 ? ZERO8_VEC16 : ZERO1_VEC16;
    int gridz = (nvec + block - 1) / block;
    zero_ws<<<gridz, block, 0, stream>>>((uint4*)d_ws, nvec);

    int grid1 = (n + block - 1) / block;                   // 1563
    int grid2 = (TABLE_VEC4 + block - 1) / block;          // 79

    if (xcd8) {
        loss_kernel<NXCD><<<grid1, block, 0, stream>>>(pred, gt2d, l2i, imgsh, ids, table, n);
        seg_reduce<NXCD><<<grid2, block, 0, stream>>>(table, acc, ticket, out);
    } else {
        loss_kernel<1><<<grid1, block, 0, stream>>>(pred, gt2d, l2i, imgsh, ids, table, n);
        seg_reduce<1><<<grid2, block, 0, stream>>>(table, acc, ticket, out);
    }
}